// Round 9
// baseline (79.413 us; speedup 1.0000x reference)
//
#include <hip/hip_runtime.h>
#include <hip/hip_bf16.h>

typedef short bf16x8 __attribute__((ext_vector_type(8)));
typedef float f32x4 __attribute__((ext_vector_type(4)));
typedef unsigned int uint;

#define TOTAL (64 * 16384)
#define ITERS 2
#define BLOCKS (TOTAL / (256 * ITERS)) // 2048
#define MAXBLOCKS 256                  // partial-max blocks

__device__ __forceinline__ uint bf16rne(float x) {
    uint b = __float_as_uint(x);
    return (b + 0x7fffu + ((b >> 16) & 1u)) >> 16;
}
__device__ __forceinline__ short bf16s(float x) { return (short)bf16rne(x); }
__device__ __forceinline__ uint pk2(float lo, float hi) {
    __hip_bfloat162 h2 = __float22bfloat162_rn(make_float2(lo, hi));
    uint u;
    __builtin_memcpy(&u, &h2, sizeof(u));
    return u;
}
__device__ __forceinline__ float relu_(float x) { return fmaxf(x, 0.0f); }
__device__ __forceinline__ float fast_sigmoid(float x) {
    return __builtin_amdgcn_rcpf(1.0f + __expf(-x));
}
__device__ __forceinline__ float dot4r(f32x4 v, float4 w) {
    return fmaf(relu_(v[0]), w.x, fmaf(relu_(v[1]), w.y,
           fmaf(relu_(v[2]), w.z, relu_(v[3]) * w.w)));
}
__device__ __forceinline__ bf16x8 u4bf(uint4 u) {
    bf16x8 r;
    __builtin_memcpy(&r, &u, sizeof(r));
    return r;
}

// ------- per-block max of criticality -> ws[blockIdx] (plain store) ----------
__global__ __launch_bounds__(256) void crit_max_kernel(
        const float* __restrict__ crit, float* __restrict__ ws, int n4) {
    __shared__ float smax[4];
    const int tid = threadIdx.x;
    float m = 0.0f;
    const float4* c4 = (const float4*)crit;
    for (int i = blockIdx.x * 256 + tid; i < n4; i += gridDim.x * 256) {
        float4 v = c4[i];
        m = fmaxf(fmaxf(m, v.x), fmaxf(fmaxf(v.y, v.z), v.w));
    }
#pragma unroll
    for (int off = 32; off > 0; off >>= 1)
        m = fmaxf(m, __shfl_xor(m, off));
    if ((tid & 63) == 0) smax[tid >> 6] = m;
    __syncthreads();
    if (tid == 0)
        ws[blockIdx.x] = fmaxf(fmaxf(smax[0], smax[1]), fmaxf(smax[2], smax[3]));
}

// -------- fused MFMA risk kernel: zero-permute layout-matched pipeline -------
// launch_bounds(256,6): VGPR cap 84 (natural pressure ~64) -> 24 waves/CU,
// double the (256,3) occupancy that left the chain latency exposed.
__global__ __launch_bounds__(256, 6) void risk_mfma_kernel(
        const float* __restrict__ tp,   const float* __restrict__ crit,
        const float* __restrict__ conn, const float* __restrict__ sens,
        const float* __restrict__ bv,   const float* __restrict__ dsv,
        const float* __restrict__ comp, const float* __restrict__ rt,
        const float* __restrict__ sev,
        const float* __restrict__ ctxW1, const float* __restrict__ ctxb1,
        const float* __restrict__ ctxW2, const float* __restrict__ ctxb2,
        const float* __restrict__ ctxW3, const float* __restrict__ ctxb3,
        const float* __restrict__ pW1,  const float* __restrict__ pb1,
        const float* __restrict__ pW2,  const float* __restrict__ pb2,
        const float* __restrict__ pW3,  const float* __restrict__ pb3,
        const float* __restrict__ pWo,  const float* __restrict__ pbo,
        const float* __restrict__ w_threat, const float* __restrict__ w_impact,
        const float* __restrict__ w_vuln,   const float* __restrict__ w_ctx,
        const float* __restrict__ ws_part,
        float* __restrict__ out) {
    const int lane = threadIdx.x & 63;
    const int g    = lane >> 4;   // 0..3 (tile ownership)
    const int c    = lane & 15;   // 0..15 (column)

    const bf16x8 z8 = {0,0,0,0,0,0,0,0};
    const f32x4  z4 = {0.f,0.f,0.f,0.f};

    // ---- global max from 256 partials (wave-redundant, ~negligible) ----
    float m;
    {
        float4 pm4 = ((const float4*)ws_part)[lane];
        float pm = fmaxf(fmaxf(pm4.x, pm4.y), fmaxf(pm4.z, pm4.w));
#pragma unroll
        for (int off = 32; off > 0; off >>= 1)
            pm = fmaxf(pm, __shfl_xor(pm, off));
        m = pm;
    }

    // ---- uniform scalars ----
    const float wt  = w_threat[0], wi = w_impact[0], wv = w_vuln[0], wc = w_ctx[0];
    const float inv_tw = 1.0f / (wt + wi + wv + wc);
    const float imul = (m > 0.0f) ? 1.0f / fmaxf(m, 1e-12f) : 1.0f;
    const float wcn = wc * inv_tw;
    const float cb3 = ctxb3[0];
    const float pbo0 = pbo[0];

    // ---- A-operand weight fragments (lane (g,c): A[row=c][k=8g+i]) ----
    bf16x8 cwAll = z8;
    cwAll[0] = bf16s(ctxW1[c]);
    cwAll[1] = bf16s(ctxW1[16 + c]);
    cwAll[2] = bf16s(ctxW1[32 + c]);
    cwAll[3] = bf16s(ctxW1[48 + c]);
    cwAll[4] = bf16s(ctxb1[c]);
    bf16x8 cw2All = z8;
    if (c < 8) {
#pragma unroll
        for (int i = 0; i < 4; ++i)
            cw2All[i] = bf16s(ctxW2[(4 * g + i) * 8 + c]);
    }
    bf16x8 w1All[4];
#pragma unroll
    for (int nt = 0; nt < 4; ++nt) {
        bf16x8 f = z8;
        f[0] = bf16s(pW1[nt * 16 + c]);
        f[4] = bf16s(pb1[nt * 16 + c]);
        f[5] = bf16s(pW1[64 + nt * 16 + c]);
        f[6] = bf16s(pW1[128 + nt * 16 + c]);
        f[7] = bf16s(pW1[192 + nt * 16 + c]);
        w1All[nt] = f;
    }
    bf16x8 w2A[2][2];
#pragma unroll
    for (int mt = 0; mt < 2; ++mt)
#pragma unroll
        for (int kf = 0; kf < 2; ++kf) {
            bf16x8 f;
#pragma unroll
            for (int i = 0; i < 4; ++i)
                f[i] = bf16s(pW2[(kf * 32 + 4 * g + i) * 32 + mt * 16 + c]);
#pragma unroll
            for (int i = 4; i < 8; ++i)
                f[i] = bf16s(pW2[(kf * 32 + 16 + 4 * g + (i - 4)) * 32 + mt * 16 + c]);
            w2A[mt][kf] = f;
        }
    bf16x8 w3A;
#pragma unroll
    for (int i = 0; i < 4; ++i) w3A[i] = bf16s(pW3[(4 * g + i) * 16 + c]);
#pragma unroll
    for (int i = 4; i < 8; ++i) w3A[i] = bf16s(pW3[(16 + 4 * g + (i - 4)) * 16 + c]);

    f32x4 b2i[2];
#pragma unroll
    for (int mt = 0; mt < 2; ++mt) {
        float4 t = ((const float4*)pb2)[mt * 4 + g];
        b2i[mt] = (f32x4){t.x, t.y, t.z, t.w};
    }
    float4 t3 = ((const float4*)pb3)[g];
    f32x4 b3i = (f32x4){t3.x, t3.y, t3.z, t3.w};
    f32x4 cb2i = z4;
    float4 cw3v = make_float4(0.f, 0.f, 0.f, 0.f);
    if (g < 2) {
        float4 tb = ((const float4*)ctxb2)[g];
        cb2i = (f32x4){tb.x, tb.y, tb.z, tb.w};
        cw3v = ((const float4*)ctxW3)[g];
    }
    float4 wog = ((const float4*)pWo)[g];

    const int eblock = blockIdx.x * (256 * ITERS);

#pragma unroll 1
    for (int it = 0; it < ITERS; ++it) {
        const int ewave = eblock + it * 256 + (int)(threadIdx.x >> 6) * 64;
        // -------- phase 1: per-element components (element = own lane) -------
        uint4 fv;
        float pbase;
        {
            const int e = ewave + lane;
            float tpv = tp[e], cv = crit[e], cnv = conn[e], snv = sens[e];
            float bvv = bv[e], dvv = dsv[e], cpv = comp[e], rtv = rt[e], svv = sev[e];
            float threat = fast_sigmoid(3.0f * tpv);
            float impact = cv * imul;
            float vuln   = svv * 0.1f;
            float invrt  = __builtin_amdgcn_rcpf(rtv + 1e-6f);
            pbase = (wt * threat + wi * impact + wv * vuln) * inv_tw;
            fv.x = pk2(bvv, dvv);
            fv.y = pk2(cpv, invrt);
            fv.z = pk2(1.0f, cv);
            fv.w = pk2(cnv, snv);
        }
        uint4 Bt[4];
#pragma unroll
        for (int t = 0; t < 4; ++t) {
            bool sel = (g == t);
            Bt[t].x = sel ? fv.x : 0u;
            Bt[t].y = sel ? fv.y : 0u;
            Bt[t].z = sel ? fv.z : 0u;
            Bt[t].w = sel ? fv.w : 0u;
        }
        // -------- ctx MLP: 4 independent tile chains -------------------------
        float pcv[4];
#pragma unroll
        for (int t = 0; t < 4; ++t) {
            f32x4 cc1 = __builtin_amdgcn_mfma_f32_16x16x32_bf16(cwAll, u4bf(Bt[t]), z4, 0, 0, 0);
            uint4 bu;
            bu.x = pk2(relu_(cc1[0]), relu_(cc1[1]));
            bu.y = pk2(relu_(cc1[2]), relu_(cc1[3]));
            bu.z = 0u;
            bu.w = 0u;
            f32x4 cc2 = __builtin_amdgcn_mfma_f32_16x16x32_bf16(cw2All, u4bf(bu), cb2i, 0, 0, 0);
            pcv[t] = dot4r(cc2, cw3v);
        }
#pragma unroll
        for (int t = 0; t < 4; ++t) {
            pcv[t] += __shfl_xor(pcv[t], 16);
            pcv[t] += __shfl_xor(pcv[t], 32);
        }
        float pcsel = (g == 0) ? pcv[0] : (g == 1) ? pcv[1] : (g == 2) ? pcv[2] : pcv[3];
        float ctxr  = fast_sigmoid(pcsel + cb3);
        float base  = fmaf(wcn, ctxr, pbase);
        uint  bb    = bf16rne(base);
        // -------- prop MLP: 4 independent tile chains ------------------------
        float pv[4];
#pragma unroll
        for (int t = 0; t < 4; ++t) {
            uint4 pB;
            pB.x = (g == t) ? bb : 0u;
            pB.y = Bt[t].y;
            pB.z = Bt[t].z;
            pB.w = Bt[t].w;
            bf16x8 bp = u4bf(pB);
            uint l1p[4][2];
#pragma unroll
            for (int nt = 0; nt < 4; ++nt) {
                f32x4 c1 = __builtin_amdgcn_mfma_f32_16x16x32_bf16(w1All[nt], bp, z4, 0, 0, 0);
                l1p[nt][0] = pk2(relu_(c1[0]), relu_(c1[1]));
                l1p[nt][1] = pk2(relu_(c1[2]), relu_(c1[3]));
            }
            uint4 B0 = make_uint4(l1p[0][0], l1p[0][1], l1p[1][0], l1p[1][1]);
            uint4 B1 = make_uint4(l1p[2][0], l1p[2][1], l1p[3][0], l1p[3][1]);
            bf16x8 b0 = u4bf(B0), b1 = u4bf(B1);
            uint l2p[2][2];
#pragma unroll
            for (int mt = 0; mt < 2; ++mt) {
                f32x4 acc = __builtin_amdgcn_mfma_f32_16x16x32_bf16(w2A[mt][0], b0, b2i[mt], 0, 0, 0);
                f32x4 c2  = __builtin_amdgcn_mfma_f32_16x16x32_bf16(w2A[mt][1], b1, acc, 0, 0, 0);
                l2p[mt][0] = pk2(relu_(c2[0]), relu_(c2[1]));
                l2p[mt][1] = pk2(relu_(c2[2]), relu_(c2[3]));
            }
            uint4 B3 = make_uint4(l2p[0][0], l2p[0][1], l2p[1][0], l2p[1][1]);
            f32x4 c3 = __builtin_amdgcn_mfma_f32_16x16x32_bf16(w3A, u4bf(B3), b3i, 0, 0, 0);
            pv[t] = dot4r(c3, wog);
        }
#pragma unroll
        for (int t = 0; t < 4; ++t) {
            pv[t] += __shfl_xor(pv[t], 16);
            pv[t] += __shfl_xor(pv[t], 32);
        }
        float psel = (g == 0) ? pv[0] : (g == 1) ? pv[1] : (g == 2) ? pv[2] : pv[3];
        out[ewave + lane] = fast_sigmoid(psel + pbo0);
    }
}

extern "C" void kernel_launch(void* const* d_in, const int* in_sizes, int n_in,
                              void* d_out, int out_size, void* d_ws, size_t ws_size,
                              hipStream_t stream) {
    const float* tp    = (const float*)d_in[0];
    const float* crit  = (const float*)d_in[1];
    const float* conn  = (const float*)d_in[2];
    const float* sens  = (const float*)d_in[3];
    const float* bv    = (const float*)d_in[4];
    const float* dsv   = (const float*)d_in[5];
    const float* comp  = (const float*)d_in[6];
    const float* rt    = (const float*)d_in[7];
    const float* sev   = (const float*)d_in[8];
    const float* ctxW1 = (const float*)d_in[9];
    const float* ctxb1 = (const float*)d_in[10];
    const float* ctxW2 = (const float*)d_in[11];
    const float* ctxb2 = (const float*)d_in[12];
    const float* ctxW3 = (const float*)d_in[13];
    const float* ctxb3 = (const float*)d_in[14];
    const float* pW1   = (const float*)d_in[15];
    const float* pb1   = (const float*)d_in[16];
    const float* pW2   = (const float*)d_in[17];
    const float* pb2   = (const float*)d_in[18];
    const float* pW3   = (const float*)d_in[19];
    const float* pb3   = (const float*)d_in[20];
    const float* pWo   = (const float*)d_in[21];
    const float* pbo   = (const float*)d_in[22];
    const float* w_t   = (const float*)d_in[23];
    const float* w_i   = (const float*)d_in[24];
    const float* w_v   = (const float*)d_in[25];
    const float* w_c   = (const float*)d_in[26];

    float* ws_part = (float*)d_ws;
    float* out = (float*)d_out;

    crit_max_kernel<<<MAXBLOCKS, 256, 0, stream>>>(crit, ws_part, TOTAL / 4);
    risk_mfma_kernel<<<BLOCKS, 256, 0, stream>>>(
        tp, crit, conn, sens, bv, dsv, comp, rt, sev,
        ctxW1, ctxb1, ctxW2, ctxb2, ctxW3, ctxb3,
        pW1, pb1, pW2, pb2, pW3, pb3, pWo, pbo,
        w_t, w_i, w_v, w_c, ws_part, out);
}

// Round 10
// 37.508 us; speedup vs baseline: 2.1172x; 2.1172x over previous
//
#include <hip/hip_runtime.h>
#include <hip/hip_bf16.h>

typedef short bf16x8 __attribute__((ext_vector_type(8)));
typedef float f32x4 __attribute__((ext_vector_type(4)));
typedef unsigned int uint;

#define TOTAL (64 * 16384)
#define BLOCKS (TOTAL / 256) // 4096
#define MAXBLOCKS 256        // partial-max blocks

// d_ws layout (bytes):
//   0     : float part[256]    (crit per-block maxima)
//   2048  : float scal[8]      (wtn,win,wvn,wcn, imul,cb3,pbo0,0)
//   4096  : uint4 frag[17][64] (per-lane fragments, see FRAG_* indices)
#define WS_PART(ws) ((float*)(ws))
#define WS_SCAL(ws) ((float*)((char*)(ws) + 2048))
#define WS_FRAG(ws) ((uint4*)((char*)(ws) + 4096))

__device__ __forceinline__ uint bf16rne(float x) {
    uint b = __float_as_uint(x);
    return (b + 0x7fffu + ((b >> 16) & 1u)) >> 16;
}
__device__ __forceinline__ short bf16s(float x) { return (short)bf16rne(x); }
__device__ __forceinline__ uint pk2(float lo, float hi) {
    __hip_bfloat162 h2 = __float22bfloat162_rn(make_float2(lo, hi));
    uint u;
    __builtin_memcpy(&u, &h2, sizeof(u));
    return u;
}
__device__ __forceinline__ float relu_(float x) { return fmaxf(x, 0.0f); }
__device__ __forceinline__ float fast_sigmoid(float x) {
    return __builtin_amdgcn_rcpf(1.0f + __expf(-x));
}
__device__ __forceinline__ float dot4r(f32x4 v, float4 w) {
    return fmaf(relu_(v[0]), w.x, fmaf(relu_(v[1]), w.y,
           fmaf(relu_(v[2]), w.z, relu_(v[3]) * w.w)));
}
__device__ __forceinline__ bf16x8 u4bf(uint4 u) {
    bf16x8 r;
    __builtin_memcpy(&r, &u, sizeof(r));
    return r;
}
__device__ __forceinline__ uint4 bfu4(bf16x8 f) {
    uint4 u;
    __builtin_memcpy(&u, &f, sizeof(u));
    return u;
}
__device__ __forceinline__ uint4 f4u4(float4 f) {
    uint4 u;
    __builtin_memcpy(&u, &f, sizeof(u));
    return u;
}

// ------- per-block max of criticality -> part[blockIdx] (plain store) --------
__global__ __launch_bounds__(256) void crit_max_kernel(
        const float* __restrict__ crit, float* __restrict__ part, int n4) {
    __shared__ float smax[4];
    const int tid = threadIdx.x;
    float m = 0.0f;
    const float4* c4 = (const float4*)crit;
    for (int i = blockIdx.x * 256 + tid; i < n4; i += gridDim.x * 256) {
        float4 v = c4[i];
        m = fmaxf(fmaxf(m, v.x), fmaxf(fmaxf(v.y, v.z), v.w));
    }
#pragma unroll
    for (int off = 32; off > 0; off >>= 1)
        m = fmaxf(m, __shfl_xor(m, off));
    if ((tid & 63) == 0) smax[tid >> 6] = m;
    __syncthreads();
    if (tid == 0)
        part[blockIdx.x] = fmaxf(fmaxf(smax[0], smax[1]), fmaxf(smax[2], smax[3]));
}

// ------- one-wave prep: build per-lane weight fragments + scalars ------------
__global__ __launch_bounds__(64) void prep_kernel(
        const float* __restrict__ ctxW1, const float* __restrict__ ctxb1,
        const float* __restrict__ ctxW2, const float* __restrict__ ctxb2,
        const float* __restrict__ ctxW3, const float* __restrict__ ctxb3,
        const float* __restrict__ pW1,  const float* __restrict__ pb1,
        const float* __restrict__ pW2,  const float* __restrict__ pb2,
        const float* __restrict__ pW3,  const float* __restrict__ pb3,
        const float* __restrict__ pWo,  const float* __restrict__ pbo,
        const float* __restrict__ w_threat, const float* __restrict__ w_impact,
        const float* __restrict__ w_vuln,   const float* __restrict__ w_ctx,
        void* __restrict__ ws) {
    const int lane = threadIdx.x;
    const int g    = lane >> 4;
    const int c    = lane & 15;
    const bf16x8 z8 = {0,0,0,0,0,0,0,0};

    // reduce crit partials -> imul; store normalized scalars
    {
        const float* part = WS_PART(ws);
        float4 pm4 = ((const float4*)part)[lane];
        float pm = fmaxf(fmaxf(pm4.x, pm4.y), fmaxf(pm4.z, pm4.w));
#pragma unroll
        for (int off = 32; off > 0; off >>= 1)
            pm = fmaxf(pm, __shfl_xor(pm, off));
        if (lane == 0) {
            float wt = w_threat[0], wi = w_impact[0], wv = w_vuln[0], wc = w_ctx[0];
            float inv_tw = 1.0f / (wt + wi + wv + wc);
            float* scal = WS_SCAL(ws);
            scal[0] = wt * inv_tw;
            scal[1] = wi * inv_tw;
            scal[2] = wv * inv_tw;
            scal[3] = wc * inv_tw;
            scal[4] = (pm > 0.0f) ? 1.0f / fmaxf(pm, 1e-12f) : 1.0f;
            scal[5] = ctxb3[0];
            scal[6] = pbo[0];
            scal[7] = 0.0f;
        }
    }

    uint4* fr = WS_FRAG(ws);
    // 0: ctx L1 (replicated k, bias at i=4)
    {
        bf16x8 f = z8;
        f[0] = bf16s(ctxW1[c]);
        f[1] = bf16s(ctxW1[16 + c]);
        f[2] = bf16s(ctxW1[32 + c]);
        f[3] = bf16s(ctxW1[48 + c]);
        f[4] = bf16s(ctxb1[c]);
        fr[0 * 64 + lane] = bfu4(f);
    }
    // 1: ctx L2 (k=8g+i <-> unit 4g+i; out m=c<8)
    {
        bf16x8 f = z8;
        if (c < 8) {
#pragma unroll
            for (int i = 0; i < 4; ++i)
                f[i] = bf16s(ctxW2[(4 * g + i) * 8 + c]);
        }
        fr[1 * 64 + lane] = bfu4(f);
    }
    // 2-5: prop L1 out-tile nt (feat order [base,-,-,-,1,crit,conn,sens])
#pragma unroll
    for (int nt = 0; nt < 4; ++nt) {
        bf16x8 f = z8;
        f[0] = bf16s(pW1[nt * 16 + c]);
        f[4] = bf16s(pb1[nt * 16 + c]);
        f[5] = bf16s(pW1[64 + nt * 16 + c]);
        f[6] = bf16s(pW1[128 + nt * 16 + c]);
        f[7] = bf16s(pW1[192 + nt * 16 + c]);
        fr[(2 + nt) * 64 + lane] = bfu4(f);
    }
    // 6-9: prop L2 [mt][kf]
#pragma unroll
    for (int mt = 0; mt < 2; ++mt)
#pragma unroll
        for (int kf = 0; kf < 2; ++kf) {
            bf16x8 f;
#pragma unroll
            for (int i = 0; i < 4; ++i)
                f[i] = bf16s(pW2[(kf * 32 + 4 * g + i) * 32 + mt * 16 + c]);
#pragma unroll
            for (int i = 4; i < 8; ++i)
                f[i] = bf16s(pW2[(kf * 32 + 16 + 4 * g + (i - 4)) * 32 + mt * 16 + c]);
            fr[(6 + mt * 2 + kf) * 64 + lane] = bfu4(f);
        }
    // 10: prop L3
    {
        bf16x8 f;
#pragma unroll
        for (int i = 0; i < 4; ++i) f[i] = bf16s(pW3[(4 * g + i) * 16 + c]);
#pragma unroll
        for (int i = 4; i < 8; ++i) f[i] = bf16s(pW3[(16 + 4 * g + (i - 4)) * 16 + c]);
        fr[10 * 64 + lane] = bfu4(f);
    }
    // 11-12: pb2 tiles; 13: pb3; 14: ctxb2 (g<2 else 0); 15: ctxW3 (g<2 else 0); 16: pWo
    fr[11 * 64 + lane] = f4u4(((const float4*)pb2)[g]);
    fr[12 * 64 + lane] = f4u4(((const float4*)pb2)[4 + g]);
    fr[13 * 64 + lane] = f4u4(((const float4*)pb3)[g]);
    float4 zf = make_float4(0.f, 0.f, 0.f, 0.f);
    fr[14 * 64 + lane] = f4u4((g < 2) ? ((const float4*)ctxb2)[g] : zf);
    fr[15 * 64 + lane] = f4u4((g < 2) ? ((const float4*)ctxW3)[g] : zf);
    fr[16 * 64 + lane] = f4u4(((const float4*)pWo)[g]);
}

// -------- fused MFMA risk kernel: zero-permute, prepacked weights ------------
__global__ __launch_bounds__(256, 3) void risk_mfma_kernel(
        const float* __restrict__ tp,   const float* __restrict__ crit,
        const float* __restrict__ conn, const float* __restrict__ sens,
        const float* __restrict__ bv,   const float* __restrict__ dsv,
        const float* __restrict__ comp, const float* __restrict__ rt,
        const float* __restrict__ sev,
        const void* __restrict__ ws,
        float* __restrict__ out) {
    const int lane = threadIdx.x & 63;
    const int g    = lane >> 4;
    const f32x4 z4 = {0.f,0.f,0.f,0.f};

    // scalars (uniform)
    const float* scal = WS_SCAL(ws);
    const float wtn = scal[0], win = scal[1], wvn = scal[2], wcn = scal[3];
    const float imul = scal[4], cb3 = scal[5], pbo0 = scal[6];

    // prepacked per-lane fragments: 17 coalesced 16B loads
    const uint4* fr = WS_FRAG(ws);
    bf16x8 cwAll  = u4bf(fr[0 * 64 + lane]);
    bf16x8 cw2All = u4bf(fr[1 * 64 + lane]);
    bf16x8 w1All[4];
#pragma unroll
    for (int nt = 0; nt < 4; ++nt) w1All[nt] = u4bf(fr[(2 + nt) * 64 + lane]);
    bf16x8 w2A[2][2];
#pragma unroll
    for (int mt = 0; mt < 2; ++mt)
#pragma unroll
        for (int kf = 0; kf < 2; ++kf)
            w2A[mt][kf] = u4bf(fr[(6 + mt * 2 + kf) * 64 + lane]);
    bf16x8 w3A = u4bf(fr[10 * 64 + lane]);
    f32x4 b2i[2], b3i, cb2i;
    float4 cw3v, wog;
    __builtin_memcpy(&b2i[0], &fr[11 * 64 + lane], 16);
    __builtin_memcpy(&b2i[1], &fr[12 * 64 + lane], 16);
    __builtin_memcpy(&b3i,    &fr[13 * 64 + lane], 16);
    __builtin_memcpy(&cb2i,   &fr[14 * 64 + lane], 16);
    __builtin_memcpy(&cw3v,   &fr[15 * 64 + lane], 16);
    __builtin_memcpy(&wog,    &fr[16 * 64 + lane], 16);

    const int ewave = blockIdx.x * 256 + (int)(threadIdx.x >> 6) * 64;

    // -------- phase 1: per-element components (element = own lane) -----------
    uint4 fv;
    float pbase;
    {
        const int e = ewave + lane;
        float tpv = tp[e], cv = crit[e], cnv = conn[e], snv = sens[e];
        float bvv = bv[e], dvv = dsv[e], cpv = comp[e], rtv = rt[e], svv = sev[e];
        float threat = fast_sigmoid(3.0f * tpv);
        float impact = cv * imul;
        float vuln   = svv * 0.1f;
        float invrt  = __builtin_amdgcn_rcpf(rtv + 1e-6f);
        pbase = fmaf(wtn, threat, fmaf(win, impact, wvn * vuln));
        fv.x = pk2(bvv, dvv);
        fv.y = pk2(cpv, invrt);
        fv.z = pk2(1.0f, cv);
        fv.w = pk2(cnv, snv);
    }
    uint4 Bt[4];
#pragma unroll
    for (int t = 0; t < 4; ++t) {
        bool sel = (g == t);
        Bt[t].x = sel ? fv.x : 0u;
        Bt[t].y = sel ? fv.y : 0u;
        Bt[t].z = sel ? fv.z : 0u;
        Bt[t].w = sel ? fv.w : 0u;
    }
    // -------- ctx MLP: 4 independent tile chains -----------------------------
    float pcv[4];
#pragma unroll
    for (int t = 0; t < 4; ++t) {
        f32x4 cc1 = __builtin_amdgcn_mfma_f32_16x16x32_bf16(cwAll, u4bf(Bt[t]), z4, 0, 0, 0);
        uint4 bu;
        bu.x = pk2(relu_(cc1[0]), relu_(cc1[1]));
        bu.y = pk2(relu_(cc1[2]), relu_(cc1[3]));
        bu.z = 0u;
        bu.w = 0u;
        f32x4 cc2 = __builtin_amdgcn_mfma_f32_16x16x32_bf16(cw2All, u4bf(bu), cb2i, 0, 0, 0);
        pcv[t] = dot4r(cc2, cw3v);
    }
#pragma unroll
    for (int t = 0; t < 4; ++t) {
        pcv[t] += __shfl_xor(pcv[t], 16);
        pcv[t] += __shfl_xor(pcv[t], 32);
    }
    float pcsel = (g == 0) ? pcv[0] : (g == 1) ? pcv[1] : (g == 2) ? pcv[2] : pcv[3];
    float ctxr  = fast_sigmoid(pcsel + cb3);
    float base  = fmaf(wcn, ctxr, pbase);
    uint  bb    = bf16rne(base);
    // -------- prop MLP: 4 independent tile chains ----------------------------
    float pv[4];
#pragma unroll
    for (int t = 0; t < 4; ++t) {
        uint4 pB;
        pB.x = (g == t) ? bb : 0u;
        pB.y = Bt[t].y;
        pB.z = Bt[t].z;
        pB.w = Bt[t].w;
        bf16x8 bp = u4bf(pB);
        uint l1p[4][2];
#pragma unroll
        for (int nt = 0; nt < 4; ++nt) {
            f32x4 c1 = __builtin_amdgcn_mfma_f32_16x16x32_bf16(w1All[nt], bp, z4, 0, 0, 0);
            l1p[nt][0] = pk2(relu_(c1[0]), relu_(c1[1]));
            l1p[nt][1] = pk2(relu_(c1[2]), relu_(c1[3]));
        }
        uint4 B0 = make_uint4(l1p[0][0], l1p[0][1], l1p[1][0], l1p[1][1]);
        uint4 B1 = make_uint4(l1p[2][0], l1p[2][1], l1p[3][0], l1p[3][1]);
        bf16x8 b0 = u4bf(B0), b1 = u4bf(B1);
        uint l2p[2][2];
#pragma unroll
        for (int mt = 0; mt < 2; ++mt) {
            f32x4 acc = __builtin_amdgcn_mfma_f32_16x16x32_bf16(w2A[mt][0], b0, b2i[mt], 0, 0, 0);
            f32x4 c2  = __builtin_amdgcn_mfma_f32_16x16x32_bf16(w2A[mt][1], b1, acc, 0, 0, 0);
            l2p[mt][0] = pk2(relu_(c2[0]), relu_(c2[1]));
            l2p[mt][1] = pk2(relu_(c2[2]), relu_(c2[3]));
        }
        uint4 B3 = make_uint4(l2p[0][0], l2p[0][1], l2p[1][0], l2p[1][1]);
        f32x4 c3 = __builtin_amdgcn_mfma_f32_16x16x32_bf16(w3A, u4bf(B3), b3i, 0, 0, 0);
        pv[t] = dot4r(c3, wog);
    }
#pragma unroll
    for (int t = 0; t < 4; ++t) {
        pv[t] += __shfl_xor(pv[t], 16);
        pv[t] += __shfl_xor(pv[t], 32);
    }
    float psel = (g == 0) ? pv[0] : (g == 1) ? pv[1] : (g == 2) ? pv[2] : pv[3];
    out[ewave + lane] = fast_sigmoid(psel + pbo0);
}

extern "C" void kernel_launch(void* const* d_in, const int* in_sizes, int n_in,
                              void* d_out, int out_size, void* d_ws, size_t ws_size,
                              hipStream_t stream) {
    const float* tp    = (const float*)d_in[0];
    const float* crit  = (const float*)d_in[1];
    const float* conn  = (const float*)d_in[2];
    const float* sens  = (const float*)d_in[3];
    const float* bv    = (const float*)d_in[4];
    const float* dsv   = (const float*)d_in[5];
    const float* comp  = (const float*)d_in[6];
    const float* rt    = (const float*)d_in[7];
    const float* sev   = (const float*)d_in[8];
    const float* ctxW1 = (const float*)d_in[9];
    const float* ctxb1 = (const float*)d_in[10];
    const float* ctxW2 = (const float*)d_in[11];
    const float* ctxb2 = (const float*)d_in[12];
    const float* ctxW3 = (const float*)d_in[13];
    const float* ctxb3 = (const float*)d_in[14];
    const float* pW1   = (const float*)d_in[15];
    const float* pb1   = (const float*)d_in[16];
    const float* pW2   = (const float*)d_in[17];
    const float* pb2   = (const float*)d_in[18];
    const float* pW3   = (const float*)d_in[19];
    const float* pb3   = (const float*)d_in[20];
    const float* pWo   = (const float*)d_in[21];
    const float* pbo   = (const float*)d_in[22];
    const float* w_t   = (const float*)d_in[23];
    const float* w_i   = (const float*)d_in[24];
    const float* w_v   = (const float*)d_in[25];
    const float* w_c   = (const float*)d_in[26];

    float* out = (float*)d_out;

    crit_max_kernel<<<MAXBLOCKS, 256, 0, stream>>>(crit, WS_PART(d_ws), TOTAL / 4);
    prep_kernel<<<1, 64, 0, stream>>>(
        ctxW1, ctxb1, ctxW2, ctxb2, ctxW3, ctxb3,
        pW1, pb1, pW2, pb2, pW3, pb3, pWo, pbo,
        w_t, w_i, w_v, w_c, d_ws);
    risk_mfma_kernel<<<BLOCKS, 256, 0, stream>>>(
        tp, crit, conn, sens, bv, dsv, comp, rt, sev, d_ws, out);
}